// Round 1
// baseline (7204.417 us; speedup 1.0000x reference)
//
#include <hip/hip_runtime.h>

#define U_N 100000
#define I_N 50000
#define D_N 128
#define B_N 4
#define E_N 500000

// ---------------------------------------------------------------------------
// Scatter: 32 lanes per edge, each lane owns 4 consecutive floats (float4).
// acc_u[b][u][:] += w * item_emb[i][:];  acc_i[b][i][:] += w * user_emb[u][:]
// ---------------------------------------------------------------------------
__global__ __launch_bounds__(256) void scatter_kernel(
    const float* __restrict__ user_emb, const float* __restrict__ item_emb,
    const int* __restrict__ eu, const int* __restrict__ ei,
    const float* __restrict__ ew,
    float* __restrict__ acc_u, float* __restrict__ acc_i)
{
    unsigned long long tid = (unsigned long long)blockIdx.x * 256ull + threadIdx.x;
    unsigned long long edge = tid >> 5;
    int g = (int)(tid & 31ull);
    if (edge >= (unsigned long long)B_N * E_N) return;

    int b = (int)(edge / E_N);
    int u = eu[edge];
    int i = ei[edge];
    float w = ew[edge];
    int d0 = g * 4;

    float4 iv = *reinterpret_cast<const float4*>(item_emb + (size_t)i * D_N + d0);
    float* du = acc_u + ((size_t)b * U_N + (size_t)u) * D_N + d0;
    atomicAdd(du + 0, w * iv.x);
    atomicAdd(du + 1, w * iv.y);
    atomicAdd(du + 2, w * iv.z);
    atomicAdd(du + 3, w * iv.w);

    float4 uv = *reinterpret_cast<const float4*>(user_emb + (size_t)u * D_N + d0);
    float* di = acc_i + ((size_t)b * I_N + (size_t)i) * D_N + d0;
    atomicAdd(di + 0, w * uv.x);
    atomicAdd(di + 1, w * uv.y);
    atomicAdd(di + 2, w * uv.z);
    atomicAdd(di + 3, w * uv.w);
}

__device__ inline float4 prelu4(float4 v, float a) {
    float4 r;
    r.x = v.x >= 0.f ? v.x : a * v.x;
    r.y = v.y >= 0.f ? v.y : a * v.y;
    r.z = v.z >= 0.f ? v.z : a * v.z;
    r.w = v.w >= 0.f ? v.w : a * v.w;
    return r;
}

// ---------------------------------------------------------------------------
// Row-GEMV + prelu, in place on acc (= single_* region), plus mean-over-b
// pre-activation -> multi_* region.
// Block: 256 threads = 32 users x 8 col-groups (16 cols each).
// Each thread computes Y[b][u][c0..c0+15] for all 4 behaviors of ONE user,
// so the b-mean is thread-local. In-place safe: all reads of this block's
// rows happen before __syncthreads(); stores after.
// ---------------------------------------------------------------------------
__global__ __launch_bounds__(256) void rowgemm_kernel(
    const float* __restrict__ W,      // [D][D] row-major (W[d][o])
    float* __restrict__ acc,          // [B][N][D] in: accumulators, out: single
    float* __restrict__ multi,        // [N][D]
    int N, const float* __restrict__ alpha_p)
{
    __shared__ float wlds[D_N][D_N];   // 64 KiB
    for (int idx = threadIdx.x; idx < D_N * D_N / 4; idx += 256) {
        reinterpret_cast<float4*>(&wlds[0][0])[idx] =
            reinterpret_cast<const float4*>(W)[idx];
    }
    __syncthreads();

    float alpha = alpha_p[0];
    int uu = threadIdx.x & 31;
    int cg = threadIdx.x >> 5;
    int c0 = cg * 16;
    int u  = blockIdx.x * 32 + uu;
    bool valid = (u < N);
    int ur = valid ? u : (N - 1);   // clamp: dead reads stay in this block's rows

    float4 acc4[4][4];  // [b][c4] -> cols c0 + c4*4 .. +3
    #pragma unroll
    for (int b = 0; b < 4; ++b)
        #pragma unroll
        for (int c = 0; c < 4; ++c)
            acc4[b][c] = make_float4(0.f, 0.f, 0.f, 0.f);

    const float* arow[4];
    #pragma unroll
    for (int b = 0; b < 4; ++b)
        arow[b] = acc + ((size_t)b * (size_t)N + (size_t)ur) * D_N;

    for (int k4 = 0; k4 < D_N / 4; ++k4) {
        float4 a[4];
        #pragma unroll
        for (int b = 0; b < 4; ++b)
            a[b] = *reinterpret_cast<const float4*>(arow[b] + k4 * 4);
        #pragma unroll
        for (int kk = 0; kk < 4; ++kk) {
            float4 wv[4];
            #pragma unroll
            for (int c = 0; c < 4; ++c)
                wv[c] = *reinterpret_cast<const float4*>(&wlds[k4 * 4 + kk][c0 + c * 4]);
            #pragma unroll
            for (int b = 0; b < 4; ++b) {
                float ak = (kk == 0) ? a[b].x : (kk == 1) ? a[b].y
                         : (kk == 2) ? a[b].z : a[b].w;
                #pragma unroll
                for (int c = 0; c < 4; ++c) {
                    acc4[b][c].x += ak * wv[c].x;
                    acc4[b][c].y += ak * wv[c].y;
                    acc4[b][c].z += ak * wv[c].z;
                    acc4[b][c].w += ak * wv[c].w;
                }
            }
        }
    }

    __syncthreads();   // all reads of this block's acc rows complete

    if (valid) {
        // mean over b (pre-activation), then prelu
        #pragma unroll
        for (int c = 0; c < 4; ++c) {
            float4 m;
            m.x = 0.25f * (acc4[0][c].x + acc4[1][c].x + acc4[2][c].x + acc4[3][c].x);
            m.y = 0.25f * (acc4[0][c].y + acc4[1][c].y + acc4[2][c].y + acc4[3][c].y);
            m.z = 0.25f * (acc4[0][c].z + acc4[1][c].z + acc4[2][c].z + acc4[3][c].z);
            m.w = 0.25f * (acc4[0][c].w + acc4[1][c].w + acc4[2][c].w + acc4[3][c].w);
            *reinterpret_cast<float4*>(multi + (size_t)u * D_N + c0 + c * 4) =
                prelu4(m, alpha);
        }
        #pragma unroll
        for (int b = 0; b < 4; ++b) {
            float* srow = acc + ((size_t)b * (size_t)N + (size_t)u) * D_N + c0;
            #pragma unroll
            for (int c = 0; c < 4; ++c)
                *reinterpret_cast<float4*>(srow + c * 4) = prelu4(acc4[b][c], alpha);
        }
    }
}

extern "C" void kernel_launch(void* const* d_in, const int* in_sizes, int n_in,
                              void* d_out, int out_size, void* d_ws, size_t ws_size,
                              hipStream_t stream) {
    const float* user_emb = (const float*)d_in[0];
    const float* item_emb = (const float*)d_in[1];
    const int*   eu       = (const int*)d_in[2];
    const int*   ei       = (const int*)d_in[3];
    const float* ew       = (const float*)d_in[4];
    const float* u_w      = (const float*)d_in[5];
    const float* i_w      = (const float*)d_in[6];
    const float* alpha    = (const float*)d_in[7];

    float* out     = (float*)d_out;
    float* multi_u = out;                                       // [U][D]
    float* multi_i = out + (size_t)U_N * D_N;                   // [I][D]
    float* acc_u   = out + (size_t)(U_N + I_N) * D_N;           // [B][U][D]
    float* acc_i   = acc_u + (size_t)B_N * U_N * D_N;           // [B][I][D]

    // zero the accumulator (= single_u + single_i) region: contiguous
    size_t acc_bytes = (size_t)B_N * (U_N + I_N) * D_N * sizeof(float);
    hipMemsetAsync(acc_u, 0, acc_bytes, stream);

    // scatter
    unsigned long long nthreads = (unsigned long long)B_N * E_N * 32ull;
    unsigned int nblocks = (unsigned int)((nthreads + 255ull) / 256ull);
    scatter_kernel<<<nblocks, 256, 0, stream>>>(user_emb, item_emb, eu, ei, ew,
                                                acc_u, acc_i);

    // GEMV + prelu + mean
    rowgemm_kernel<<<(U_N + 31) / 32, 256, 0, stream>>>(u_w, acc_u, multi_u, U_N, alpha);
    rowgemm_kernel<<<(I_N + 31) / 32, 256, 0, stream>>>(i_w, acc_i, multi_i, I_N, alpha);
}

// Round 2
// 1567.691 us; speedup vs baseline: 4.5956x; 4.5956x over previous
//
#include <hip/hip_runtime.h>

#define U_N 100000
#define I_N 50000
#define D_N 128
#define B_N 4
#define E_N 500000
#define NEDGE (B_N * E_N)            // 2,000,000 edges (flattened over [B][E])
#define NKEYU (B_N * U_N)            // 400,000 u-side destination rows
#define NKEYI (B_N * I_N)            // 200,000 i-side destination rows
#define NKEYS (NKEYU + NKEYI)        // 600,000 buckets
#define NMEMB (2 * NEDGE)            // 4,000,000 memberships
#define SCHUNK 2048
#define SNBLK ((NKEYS + SCHUNK - 1) / SCHUNK)   // 293 scan blocks

// ---------------------------------------------------------------------------
// Counting sort phase 1: histogram of destination keys.
// ---------------------------------------------------------------------------
__global__ __launch_bounds__(256) void count_kernel(
    const int* __restrict__ eu, const int* __restrict__ ei, int* __restrict__ cnt)
{
    int e = blockIdx.x * 256 + threadIdx.x;
    if (e >= NEDGE) return;
    int b = e / E_N;
    atomicAdd(&cnt[b * U_N + eu[e]], 1);
    atomicAdd(&cnt[NKEYU + b * I_N + ei[e]], 1);
}

// ---------------------------------------------------------------------------
// Hierarchical exclusive scan over cnt[NKEYS] -> offs[NKEYS+1].
// ---------------------------------------------------------------------------
__global__ __launch_bounds__(256) void scan1_kernel(
    const int* __restrict__ cnt, int* __restrict__ offs, int* __restrict__ bsum)
{
    __shared__ int s[256];
    int base = blockIdx.x * SCHUNK + threadIdx.x * 8;
    int v[8]; int tsum = 0;
    #pragma unroll
    for (int j = 0; j < 8; ++j) {
        int idx = base + j;
        v[j] = (idx < NKEYS) ? cnt[idx] : 0;
        tsum += v[j];
    }
    s[threadIdx.x] = tsum; __syncthreads();
    for (int off = 1; off < 256; off <<= 1) {
        int t = (threadIdx.x >= off) ? s[threadIdx.x - off] : 0;
        __syncthreads(); s[threadIdx.x] += t; __syncthreads();
    }
    int excl = s[threadIdx.x] - tsum;
    if (threadIdx.x == 255) bsum[blockIdx.x] = s[255];
    int run = excl;
    #pragma unroll
    for (int j = 0; j < 8; ++j) {
        int idx = base + j;
        if (idx < NKEYS) offs[idx] = run;
        run += v[j];
    }
}

__global__ __launch_bounds__(512) void scan2_kernel(int* __restrict__ bsum,
                                                    int* __restrict__ offs)
{
    __shared__ int s[512];
    int v = (threadIdx.x < SNBLK) ? bsum[threadIdx.x] : 0;
    s[threadIdx.x] = v; __syncthreads();
    for (int off = 1; off < 512; off <<= 1) {
        int t = (threadIdx.x >= off) ? s[threadIdx.x - off] : 0;
        __syncthreads(); s[threadIdx.x] += t; __syncthreads();
    }
    if (threadIdx.x < SNBLK) bsum[threadIdx.x] = s[threadIdx.x] - v;
    if (threadIdx.x == 511) offs[NKEYS] = s[511];   // total = NMEMB
}

__global__ __launch_bounds__(256) void scan3_kernel(int* __restrict__ offs,
                                                    const int* __restrict__ bsum)
{
    int add = bsum[blockIdx.x];
    int base = blockIdx.x * SCHUNK + threadIdx.x * 8;
    #pragma unroll
    for (int j = 0; j < 8; ++j) {
        int idx = base + j;
        if (idx < NKEYS) offs[idx] += add;
    }
}

// ---------------------------------------------------------------------------
// Counting sort phase 2: place edge ids into buckets (cnt re-used as rank).
// ---------------------------------------------------------------------------
__global__ __launch_bounds__(256) void fill_kernel(
    const int* __restrict__ eu, const int* __restrict__ ei,
    const int* __restrict__ offs, int* __restrict__ cnt, int* __restrict__ sorted)
{
    int e = blockIdx.x * 256 + threadIdx.x;
    if (e >= NEDGE) return;
    int b = e / E_N;
    int ku = b * U_N + eu[e];
    int r = atomicAdd(&cnt[ku], 1);
    sorted[offs[ku] + r] = e;
    int ki = NKEYU + b * I_N + ei[e];
    int r2 = atomicAdd(&cnt[ki], 1);
    sorted[offs[ki] + r2] = e;
}

// ---------------------------------------------------------------------------
// Gather: one 64-lane wave per destination row; lane owns 2 floats.
// Writes every row (zeros for empty) -> no memset of acc needed.
// ---------------------------------------------------------------------------
__global__ __launch_bounds__(256) void gather_kernel(
    const float* __restrict__ user_emb, const float* __restrict__ item_emb,
    const int* __restrict__ eu, const int* __restrict__ ei,
    const float* __restrict__ ew,
    const int* __restrict__ offs, const int* __restrict__ sorted,
    float* __restrict__ acc_u, float* __restrict__ acc_i)
{
    int row = blockIdx.x * 4 + (threadIdx.x >> 6);
    if (row >= NKEYS) return;
    int lane = threadIdx.x & 63;
    int d = lane * 2;
    int beg = offs[row], end = offs[row + 1];
    bool uside = row < NKEYU;
    const float* emb = uside ? item_emb : user_emb;
    const int* sidx  = uside ? ei : eu;
    float ax = 0.f, ay = 0.f;
    for (int p = beg; p < end; ++p) {
        int e = sorted[p];
        float w = ew[e];
        int s = sidx[e];
        float2 v = *reinterpret_cast<const float2*>(emb + (size_t)s * D_N + d);
        ax += w * v.x;
        ay += w * v.y;
    }
    float* dst = uside ? (acc_u + (size_t)row * D_N)
                       : (acc_i + (size_t)(row - NKEYU) * D_N);
    float2 o; o.x = ax; o.y = ay;
    *reinterpret_cast<float2*>(dst + d) = o;
}

__device__ inline float4 prelu4(float4 v, float a) {
    float4 r;
    r.x = v.x >= 0.f ? v.x : a * v.x;
    r.y = v.y >= 0.f ? v.y : a * v.y;
    r.z = v.z >= 0.f ? v.z : a * v.z;
    r.w = v.w >= 0.f ? v.w : a * v.w;
    return r;
}

// ---------------------------------------------------------------------------
// Row-GEMV + prelu in place on acc (single_*), b-mean pre-activation -> multi.
// ---------------------------------------------------------------------------
__global__ __launch_bounds__(256) void rowgemm_kernel(
    const float* __restrict__ W,
    float* __restrict__ acc,          // [B][N][D] in: accumulators, out: single
    float* __restrict__ multi,        // [N][D]
    int N, const float* __restrict__ alpha_p)
{
    __shared__ float wlds[D_N][D_N];
    for (int idx = threadIdx.x; idx < D_N * D_N / 4; idx += 256) {
        reinterpret_cast<float4*>(&wlds[0][0])[idx] =
            reinterpret_cast<const float4*>(W)[idx];
    }
    __syncthreads();

    float alpha = alpha_p[0];
    int uu = threadIdx.x & 31;
    int cg = threadIdx.x >> 5;
    int c0 = cg * 16;
    int u  = blockIdx.x * 32 + uu;
    bool valid = (u < N);
    int ur = valid ? u : (N - 1);

    float4 acc4[4][4];
    #pragma unroll
    for (int b = 0; b < 4; ++b)
        #pragma unroll
        for (int c = 0; c < 4; ++c)
            acc4[b][c] = make_float4(0.f, 0.f, 0.f, 0.f);

    const float* arow[4];
    #pragma unroll
    for (int b = 0; b < 4; ++b)
        arow[b] = acc + ((size_t)b * (size_t)N + (size_t)ur) * D_N;

    for (int k4 = 0; k4 < D_N / 4; ++k4) {
        float4 a[4];
        #pragma unroll
        for (int b = 0; b < 4; ++b)
            a[b] = *reinterpret_cast<const float4*>(arow[b] + k4 * 4);
        #pragma unroll
        for (int kk = 0; kk < 4; ++kk) {
            float4 wv[4];
            #pragma unroll
            for (int c = 0; c < 4; ++c)
                wv[c] = *reinterpret_cast<const float4*>(&wlds[k4 * 4 + kk][c0 + c * 4]);
            #pragma unroll
            for (int b = 0; b < 4; ++b) {
                float ak = (kk == 0) ? a[b].x : (kk == 1) ? a[b].y
                         : (kk == 2) ? a[b].z : a[b].w;
                #pragma unroll
                for (int c = 0; c < 4; ++c) {
                    acc4[b][c].x += ak * wv[c].x;
                    acc4[b][c].y += ak * wv[c].y;
                    acc4[b][c].z += ak * wv[c].z;
                    acc4[b][c].w += ak * wv[c].w;
                }
            }
        }
    }

    __syncthreads();

    if (valid) {
        #pragma unroll
        for (int c = 0; c < 4; ++c) {
            float4 m;
            m.x = 0.25f * (acc4[0][c].x + acc4[1][c].x + acc4[2][c].x + acc4[3][c].x);
            m.y = 0.25f * (acc4[0][c].y + acc4[1][c].y + acc4[2][c].y + acc4[3][c].y);
            m.z = 0.25f * (acc4[0][c].z + acc4[1][c].z + acc4[2][c].z + acc4[3][c].z);
            m.w = 0.25f * (acc4[0][c].w + acc4[1][c].w + acc4[2][c].w + acc4[3][c].w);
            *reinterpret_cast<float4*>(multi + (size_t)u * D_N + c0 + c * 4) =
                prelu4(m, alpha);
        }
        #pragma unroll
        for (int b = 0; b < 4; ++b) {
            float* srow = acc + ((size_t)b * (size_t)N + (size_t)u) * D_N + c0;
            #pragma unroll
            for (int c = 0; c < 4; ++c)
                *reinterpret_cast<float4*>(srow + c * 4) = prelu4(acc4[b][c], alpha);
        }
    }
}

extern "C" void kernel_launch(void* const* d_in, const int* in_sizes, int n_in,
                              void* d_out, int out_size, void* d_ws, size_t ws_size,
                              hipStream_t stream) {
    const float* user_emb = (const float*)d_in[0];
    const float* item_emb = (const float*)d_in[1];
    const int*   eu       = (const int*)d_in[2];
    const int*   ei       = (const int*)d_in[3];
    const float* ew       = (const float*)d_in[4];
    const float* u_w      = (const float*)d_in[5];
    const float* i_w      = (const float*)d_in[6];
    const float* alpha    = (const float*)d_in[7];

    float* out     = (float*)d_out;
    float* multi_u = out;                                       // [U][D]
    float* multi_i = out + (size_t)U_N * D_N;                   // [I][D]
    float* acc_u   = out + (size_t)(U_N + I_N) * D_N;           // [B][U][D]
    float* acc_i   = acc_u + (size_t)B_N * U_N * D_N;           // [B][I][D]

    // Scratch lives in the multi_u region (51.2 MB): only written by the
    // final rowgemm kernels, after all scratch consumers have completed.
    int* scratch = (int*)out;
    int* offs    = scratch;                    // NKEYS+1
    int* cnt     = offs + (NKEYS + 1);         // NKEYS
    int* bsum    = cnt + NKEYS;                // SNBLK (padded to 512)
    int* sorted  = bsum + 512;                 // NMEMB
    // total: ~5.2M ints = 20.8 MB < 51.2 MB

    hipMemsetAsync(cnt, 0, (size_t)NKEYS * sizeof(int), stream);
    count_kernel<<<(NEDGE + 255) / 256, 256, 0, stream>>>(eu, ei, cnt);
    scan1_kernel<<<SNBLK, 256, 0, stream>>>(cnt, offs, bsum);
    scan2_kernel<<<1, 512, 0, stream>>>(bsum, offs);
    scan3_kernel<<<SNBLK, 256, 0, stream>>>(offs, bsum);
    hipMemsetAsync(cnt, 0, (size_t)NKEYS * sizeof(int), stream);
    fill_kernel<<<(NEDGE + 255) / 256, 256, 0, stream>>>(eu, ei, offs, cnt, sorted);
    gather_kernel<<<(NKEYS + 3) / 4, 256, 0, stream>>>(
        user_emb, item_emb, eu, ei, ew, offs, sorted, acc_u, acc_i);

    rowgemm_kernel<<<(U_N + 31) / 32, 256, 0, stream>>>(u_w, acc_u, multi_u, U_N, alpha);
    rowgemm_kernel<<<(I_N + 31) / 32, 256, 0, stream>>>(i_w, acc_i, multi_i, I_N, alpha);
}

// Round 3
// 1112.042 us; speedup vs baseline: 6.4785x; 1.4097x over previous
//
#include <hip/hip_runtime.h>

#define U_N 100000
#define I_N 50000
#define D_N 128
#define B_N 4
#define E_N 500000
#define NEDGE (B_N * E_N)            // 2,000,000
#define NKEYU (4 * U_N)              // keys u*4+b
#define NKEYI (4 * I_N)
#define NKEYS (NKEYU + NKEYI)        // 600,000
#define SCHUNK 2048
#define SNBLK ((NKEYS + SCHUNK - 1) / SCHUNK)   // 293

// ---------------------------------------------------------------------------
// Y[r][:] = X[r][:] @ W   (D=128). 256 thr = 32 rows x 8 colgroups(16).
// ---------------------------------------------------------------------------
__global__ __launch_bounds__(256) void transform_kernel(
    const float* __restrict__ X, const float* __restrict__ W,
    float* __restrict__ Y, int N)
{
    __shared__ float wlds[D_N][D_N];
    for (int idx = threadIdx.x; idx < D_N * D_N / 4; idx += 256)
        reinterpret_cast<float4*>(&wlds[0][0])[idx] =
            reinterpret_cast<const float4*>(W)[idx];
    __syncthreads();

    int rr = threadIdx.x & 31;
    int cg = threadIdx.x >> 5;
    int c0 = cg * 16;
    int r  = blockIdx.x * 32 + rr;
    bool valid = (r < N);
    int rc = valid ? r : (N - 1);
    const float* xrow = X + (size_t)rc * D_N;

    float4 acc[4];
    #pragma unroll
    for (int c = 0; c < 4; ++c) acc[c] = make_float4(0.f, 0.f, 0.f, 0.f);

    for (int k4 = 0; k4 < D_N / 4; ++k4) {
        float4 a = *reinterpret_cast<const float4*>(xrow + k4 * 4);
        #pragma unroll
        for (int kk = 0; kk < 4; ++kk) {
            float ak = (kk == 0) ? a.x : (kk == 1) ? a.y : (kk == 2) ? a.z : a.w;
            #pragma unroll
            for (int c = 0; c < 4; ++c) {
                const float4 wv = *reinterpret_cast<const float4*>(
                    &wlds[k4 * 4 + kk][c0 + c * 4]);
                acc[c].x += ak * wv.x;
                acc[c].y += ak * wv.y;
                acc[c].z += ak * wv.z;
                acc[c].w += ak * wv.w;
            }
        }
    }
    if (valid) {
        #pragma unroll
        for (int c = 0; c < 4; ++c)
            *reinterpret_cast<float4*>(Y + (size_t)r * D_N + c0 + c * 4) = acc[c];
    }
}

// ---------------------------------------------------------------------------
// Counting sort. offs doubles as the counter array (destructive fill).
// ---------------------------------------------------------------------------
__global__ __launch_bounds__(256) void count_kernel(
    const int* __restrict__ eu, const int* __restrict__ ei, int* __restrict__ cnt)
{
    int e = blockIdx.x * 256 + threadIdx.x;
    if (e >= NEDGE) return;
    int b = e / E_N;
    atomicAdd(&cnt[eu[e] * 4 + b], 1);
    atomicAdd(&cnt[NKEYU + ei[e] * 4 + b], 1);
}

// in-place hierarchical exclusive scan over offs[NKEYS]
__global__ __launch_bounds__(256) void scan1_kernel(
    int* __restrict__ offs, int* __restrict__ bsum)
{
    __shared__ int s[256];
    int base = blockIdx.x * SCHUNK + threadIdx.x * 8;
    int v[8]; int tsum = 0;
    #pragma unroll
    for (int j = 0; j < 8; ++j) {
        int idx = base + j;
        v[j] = (idx < NKEYS) ? offs[idx] : 0;
        tsum += v[j];
    }
    s[threadIdx.x] = tsum; __syncthreads();
    for (int off = 1; off < 256; off <<= 1) {
        int t = (threadIdx.x >= off) ? s[threadIdx.x - off] : 0;
        __syncthreads(); s[threadIdx.x] += t; __syncthreads();
    }
    int excl = s[threadIdx.x] - tsum;
    if (threadIdx.x == 255) bsum[blockIdx.x] = s[255];
    int run = excl;
    #pragma unroll
    for (int j = 0; j < 8; ++j) {
        int idx = base + j;
        if (idx < NKEYS) offs[idx] = run;
        run += v[j];
    }
}

__global__ __launch_bounds__(512) void scan2_kernel(int* __restrict__ bsum,
                                                    int* __restrict__ offs)
{
    __shared__ int s[512];
    int v = (threadIdx.x < SNBLK) ? bsum[threadIdx.x] : 0;
    s[threadIdx.x] = v; __syncthreads();
    for (int off = 1; off < 512; off <<= 1) {
        int t = (threadIdx.x >= off) ? s[threadIdx.x - off] : 0;
        __syncthreads(); s[threadIdx.x] += t; __syncthreads();
    }
    if (threadIdx.x < SNBLK) bsum[threadIdx.x] = s[threadIdx.x] - v;
    if (threadIdx.x == 511) offs[NKEYS] = s[511];
}

__global__ __launch_bounds__(256) void scan3_kernel(int* __restrict__ offs,
                                                    const int* __restrict__ bsum)
{
    int add = bsum[blockIdx.x];
    int base = blockIdx.x * SCHUNK + threadIdx.x * 8;
    #pragma unroll
    for (int j = 0; j < 8; ++j) {
        int idx = base + j;
        if (idx < NKEYS) offs[idx] += add;
    }
}

// destructive fill: after this, offs[k] == original offs[k+1] (end pointer)
__global__ __launch_bounds__(256) void fill_kernel(
    const int* __restrict__ eu, const int* __restrict__ ei,
    const float* __restrict__ ew,
    int* __restrict__ offs, int2* __restrict__ pairs)
{
    int e = blockIdx.x * 256 + threadIdx.x;
    if (e >= NEDGE) return;
    int b = e / E_N;
    int u = eu[e], i = ei[e];
    int w = __float_as_int(ew[e]);
    int s1 = atomicAdd(&offs[u * 4 + b], 1);
    pairs[s1] = make_int2(i, w);
    int s2 = atomicAdd(&offs[NKEYU + i * 4 + b], 1);
    pairs[s2] = make_int2(u, w);
}

// ---------------------------------------------------------------------------
// Gather: one wave per destination row; lanes own 2 floats. Walks the 4
// contiguous behavior buckets (keys r*4+0..3), writes prelu'd single rows
// and the prelu'd b-mean (multi) from registers.
// ---------------------------------------------------------------------------
__global__ __launch_bounds__(256) void gather_kernel(
    const float* __restrict__ T,      // transformed source emb [Nsrc][D]
    const int2* __restrict__ pairs,
    const int* __restrict__ offs,     // end pointers
    float* __restrict__ single,       // [B][N][D]
    float* __restrict__ multi,        // [N][D]
    int N, int keybase, const float* __restrict__ alpha_p)
{
    int r = blockIdx.x * 4 + (threadIdx.x >> 6);
    if (r >= N) return;
    float alpha = alpha_p[0];
    int lane = threadIdx.x & 63;
    int d = lane * 2;
    int k0 = keybase + r * 4;
    int beg = (k0 == 0) ? 0 : offs[k0 - 1];
    float mx = 0.f, my = 0.f;
    #pragma unroll
    for (int b = 0; b < 4; ++b) {
        int end = offs[k0 + b];
        float ax = 0.f, ay = 0.f;
        for (int p = beg; p < end; ++p) {
            int2 pr = pairs[p];
            float w = __int_as_float(pr.y);
            float2 v = *reinterpret_cast<const float2*>(T + (size_t)pr.x * D_N + d);
            ax += w * v.x;
            ay += w * v.y;
        }
        mx += ax; my += ay;
        float2 o;
        o.x = ax >= 0.f ? ax : alpha * ax;
        o.y = ay >= 0.f ? ay : alpha * ay;
        *reinterpret_cast<float2*>(single + ((size_t)b * N + r) * D_N + d) = o;
        beg = end;
    }
    mx *= 0.25f; my *= 0.25f;
    float2 o;
    o.x = mx >= 0.f ? mx : alpha * mx;
    o.y = my >= 0.f ? my : alpha * my;
    *reinterpret_cast<float2*>(multi + (size_t)r * D_N + d) = o;
}

extern "C" void kernel_launch(void* const* d_in, const int* in_sizes, int n_in,
                              void* d_out, int out_size, void* d_ws, size_t ws_size,
                              hipStream_t stream) {
    const float* user_emb = (const float*)d_in[0];
    const float* item_emb = (const float*)d_in[1];
    const int*   eu       = (const int*)d_in[2];
    const int*   ei       = (const int*)d_in[3];
    const float* ew       = (const float*)d_in[4];
    const float* u_w      = (const float*)d_in[5];
    const float* i_w      = (const float*)d_in[6];
    const float* alpha    = (const float*)d_in[7];

    float* out      = (float*)d_out;
    float* multi_u  = out;                                      // [U][D]
    float* multi_i  = out + (size_t)U_N * D_N;                  // [I][D]
    float* single_u = out + (size_t)(U_N + I_N) * D_N;          // [B][U][D]
    float* single_i = single_u + (size_t)B_N * U_N * D_N;       // [B][I][D]

    // tB = user_emb @ i_w lives in multi_u's slot (written last by gather_u)
    float* tB = multi_u;   // [U][D] = 51.2 MB

    // d_ws: offs | bsum | pairs | tA   (~60.5 MB)
    char* ws   = (char*)d_ws;
    int*  offs = (int*)ws;                                   // NKEYS+1
    int*  bsum = offs + (NKEYS + 1);                         // 512
    int2* pairs = (int2*)(ws + ((((NKEYS + 1 + 512) * 4) + 255) & ~255));
    float* tA  = (float*)((char*)pairs + (size_t)NEDGE * 2 * sizeof(int2));

    hipMemsetAsync(offs, 0, (size_t)(NKEYS + 1) * sizeof(int), stream);

    transform_kernel<<<(I_N + 31) / 32, 256, 0, stream>>>(item_emb, u_w, tA, I_N);
    transform_kernel<<<(U_N + 31) / 32, 256, 0, stream>>>(user_emb, i_w, tB, U_N);

    count_kernel<<<(NEDGE + 255) / 256, 256, 0, stream>>>(eu, ei, offs);
    scan1_kernel<<<SNBLK, 256, 0, stream>>>(offs, bsum);
    scan2_kernel<<<1, 512, 0, stream>>>(bsum, offs);
    scan3_kernel<<<SNBLK, 256, 0, stream>>>(offs, bsum);
    fill_kernel<<<(NEDGE + 255) / 256, 256, 0, stream>>>(eu, ei, ew, offs, pairs);

    // i-side first: it reads tB which lives in multi_u (written by gather_u)
    gather_kernel<<<(I_N + 3) / 4, 256, 0, stream>>>(
        tB, pairs, offs, single_i, multi_i, I_N, NKEYU, alpha);
    gather_kernel<<<(U_N + 3) / 4, 256, 0, stream>>>(
        tA, pairs, offs, single_u, multi_u, U_N, 0, alpha);
}

// Round 4
// 742.838 us; speedup vs baseline: 9.6985x; 1.4970x over previous
//
#include <hip/hip_runtime.h>

#define U_N 100000
#define I_N 50000
#define D_N 128
#define B_N 4
#define E_N 500000
#define NEDGE (B_N * E_N)            // 2,000,000
#define NKEYU (4 * U_N)              // keys u*4+b
#define NKEYS (NKEYU + 4 * I_N)      // 600,000
#define NMEMB (2 * NEDGE)            // 4,000,000
#define SCHUNK 2048
#define SNBLK ((NKEYS + SCHUNK - 1) / SCHUNK)   // 293
#define TBI ((I_N + 31) / 32)        // 1563 transform blocks (item side)
#define TBU ((U_N + 31) / 32)        // 3125 transform blocks (user side)

// ---------------------------------------------------------------------------
// Fused transforms: tA = item_emb @ u_w, tB = user_emb @ i_w, one dispatch.
// 256 thr = 32 rows x 8 colgroups(16 cols).
// ---------------------------------------------------------------------------
__global__ __launch_bounds__(256) void transform2_kernel(
    const float* __restrict__ item_emb, const float* __restrict__ user_emb,
    const float* __restrict__ u_w, const float* __restrict__ i_w,
    float* __restrict__ tA, float* __restrict__ tB)
{
    const float* X; const float* W; float* Y; int N; int blk;
    if (blockIdx.x < TBI) { X = item_emb; W = u_w; Y = tA; N = I_N; blk = blockIdx.x; }
    else                  { X = user_emb; W = i_w; Y = tB; N = U_N; blk = blockIdx.x - TBI; }

    __shared__ float wlds[D_N][D_N];
    for (int idx = threadIdx.x; idx < D_N * D_N / 4; idx += 256)
        reinterpret_cast<float4*>(&wlds[0][0])[idx] =
            reinterpret_cast<const float4*>(W)[idx];
    __syncthreads();

    int rr = threadIdx.x & 31;
    int cg = threadIdx.x >> 5;
    int c0 = cg * 16;
    int r  = blk * 32 + rr;
    bool valid = (r < N);
    int rc = valid ? r : (N - 1);
    const float* xrow = X + (size_t)rc * D_N;

    float4 acc[4];
    #pragma unroll
    for (int c = 0; c < 4; ++c) acc[c] = make_float4(0.f, 0.f, 0.f, 0.f);

    for (int k4 = 0; k4 < D_N / 4; ++k4) {
        float4 a = *reinterpret_cast<const float4*>(xrow + k4 * 4);
        #pragma unroll
        for (int kk = 0; kk < 4; ++kk) {
            float ak = (kk == 0) ? a.x : (kk == 1) ? a.y : (kk == 2) ? a.z : a.w;
            #pragma unroll
            for (int c = 0; c < 4; ++c) {
                const float4 wv = *reinterpret_cast<const float4*>(
                    &wlds[k4 * 4 + kk][c0 + c * 4]);
                acc[c].x += ak * wv.x;
                acc[c].y += ak * wv.y;
                acc[c].z += ak * wv.z;
                acc[c].w += ak * wv.w;
            }
        }
    }
    if (valid) {
        #pragma unroll
        for (int c = 0; c < 4; ++c)
            *reinterpret_cast<float4*>(Y + (size_t)r * D_N + c0 + c * 4) = acc[c];
    }
}

// ---------------------------------------------------------------------------
// Count + rank: one membership per thread (4M threads, 1 atomic each).
// The atomic return value IS the membership's rank within its bucket.
// ---------------------------------------------------------------------------
__global__ __launch_bounds__(256) void count_kernel(
    const int* __restrict__ eu, const int* __restrict__ ei,
    int* __restrict__ offs, int* __restrict__ rank_u, int* __restrict__ rank_i)
{
    int t = blockIdx.x * 256 + threadIdx.x;
    if (t >= NMEMB) return;
    if (t < NEDGE) {
        int e = t;
        int key = eu[e] * 4 + e / E_N;
        rank_u[e] = atomicAdd(&offs[key], 1);
    } else {
        int e = t - NEDGE;
        int key = NKEYU + ei[e] * 4 + e / E_N;
        rank_i[e] = atomicAdd(&offs[key], 1);
    }
}

// ---------------------------------------------------------------------------
// In-place hierarchical exclusive scan over offs[NKEYS] (start pointers kept).
// ---------------------------------------------------------------------------
__global__ __launch_bounds__(256) void scan1_kernel(
    int* __restrict__ offs, int* __restrict__ bsum)
{
    __shared__ int s[256];
    int base = blockIdx.x * SCHUNK + threadIdx.x * 8;
    int v[8]; int tsum = 0;
    #pragma unroll
    for (int j = 0; j < 8; ++j) {
        int idx = base + j;
        v[j] = (idx < NKEYS) ? offs[idx] : 0;
        tsum += v[j];
    }
    s[threadIdx.x] = tsum; __syncthreads();
    for (int off = 1; off < 256; off <<= 1) {
        int t = (threadIdx.x >= off) ? s[threadIdx.x - off] : 0;
        __syncthreads(); s[threadIdx.x] += t; __syncthreads();
    }
    int excl = s[threadIdx.x] - tsum;
    if (threadIdx.x == 255) bsum[blockIdx.x] = s[255];
    int run = excl;
    #pragma unroll
    for (int j = 0; j < 8; ++j) {
        int idx = base + j;
        if (idx < NKEYS) offs[idx] = run;
        run += v[j];
    }
}

__global__ __launch_bounds__(512) void scan2_kernel(int* __restrict__ bsum,
                                                    int* __restrict__ offs)
{
    __shared__ int s[512];
    int v = (threadIdx.x < SNBLK) ? bsum[threadIdx.x] : 0;
    s[threadIdx.x] = v; __syncthreads();
    for (int off = 1; off < 512; off <<= 1) {
        int t = (threadIdx.x >= off) ? s[threadIdx.x - off] : 0;
        __syncthreads(); s[threadIdx.x] += t; __syncthreads();
    }
    if (threadIdx.x < SNBLK) bsum[threadIdx.x] = s[threadIdx.x] - v;
    if (threadIdx.x == 511) offs[NKEYS] = s[511];
}

__global__ __launch_bounds__(256) void scan3_kernel(int* __restrict__ offs,
                                                    const int* __restrict__ bsum)
{
    int add = bsum[blockIdx.x];
    int base = blockIdx.x * SCHUNK + threadIdx.x * 8;
    #pragma unroll
    for (int j = 0; j < 8; ++j) {
        int idx = base + j;
        if (idx < NKEYS) offs[idx] += add;
    }
}

// ---------------------------------------------------------------------------
// Atomic-free fill: pos = offs[key] + precomputed rank; fire-and-forget store.
// ---------------------------------------------------------------------------
__global__ __launch_bounds__(256) void fill_kernel(
    const int* __restrict__ eu, const int* __restrict__ ei,
    const float* __restrict__ ew,
    const int* __restrict__ offs,
    const int* __restrict__ rank_u, const int* __restrict__ rank_i,
    int2* __restrict__ pairs)
{
    int t = blockIdx.x * 256 + threadIdx.x;
    if (t >= NMEMB) return;
    if (t < NEDGE) {
        int e = t;
        int b = e / E_N;
        int key = eu[e] * 4 + b;
        int pos = offs[key] + rank_u[e];
        pairs[pos] = make_int2(ei[e], __float_as_int(ew[e]));
    } else {
        int e = t - NEDGE;
        int b = e / E_N;
        int key = NKEYU + ei[e] * 4 + b;
        int pos = offs[key] + rank_i[e];
        pairs[pos] = make_int2(eu[e], __float_as_int(ew[e]));
    }
}

// ---------------------------------------------------------------------------
// Gather: one wave per destination row; lanes own 2 floats; 2x-unrolled
// membership loop for memory-level parallelism. Start-pointer offs.
// ---------------------------------------------------------------------------
__global__ __launch_bounds__(256) void gather_kernel(
    const float* __restrict__ T,
    const int2* __restrict__ pairs,
    const int* __restrict__ offs,
    float* __restrict__ single,       // [B][N][D]
    float* __restrict__ multi,        // [N][D]
    int N, int keybase, const float* __restrict__ alpha_p)
{
    int r = blockIdx.x * 4 + (threadIdx.x >> 6);
    if (r >= N) return;
    float alpha = alpha_p[0];
    int lane = threadIdx.x & 63;
    int d = lane * 2;
    int k0 = keybase + r * 4;
    int beg = offs[k0];
    float mx = 0.f, my = 0.f;
    #pragma unroll
    for (int b = 0; b < 4; ++b) {
        int end = offs[k0 + b + 1];
        float ax = 0.f, ay = 0.f;
        int p = beg;
        for (; p + 1 < end; p += 2) {
            int2 pr0 = pairs[p];
            int2 pr1 = pairs[p + 1];
            float2 v0 = *reinterpret_cast<const float2*>(T + (size_t)pr0.x * D_N + d);
            float2 v1 = *reinterpret_cast<const float2*>(T + (size_t)pr1.x * D_N + d);
            float w0 = __int_as_float(pr0.y);
            float w1 = __int_as_float(pr1.y);
            ax += w0 * v0.x + w1 * v1.x;
            ay += w0 * v0.y + w1 * v1.y;
        }
        if (p < end) {
            int2 pr = pairs[p];
            float w = __int_as_float(pr.y);
            float2 v = *reinterpret_cast<const float2*>(T + (size_t)pr.x * D_N + d);
            ax += w * v.x;
            ay += w * v.y;
        }
        mx += ax; my += ay;
        float2 o;
        o.x = ax >= 0.f ? ax : alpha * ax;
        o.y = ay >= 0.f ? ay : alpha * ay;
        *reinterpret_cast<float2*>(single + ((size_t)b * N + r) * D_N + d) = o;
        beg = end;
    }
    mx *= 0.25f; my *= 0.25f;
    float2 o;
    o.x = mx >= 0.f ? mx : alpha * mx;
    o.y = my >= 0.f ? my : alpha * my;
    *reinterpret_cast<float2*>(multi + (size_t)r * D_N + d) = o;
}

extern "C" void kernel_launch(void* const* d_in, const int* in_sizes, int n_in,
                              void* d_out, int out_size, void* d_ws, size_t ws_size,
                              hipStream_t stream) {
    const float* user_emb = (const float*)d_in[0];
    const float* item_emb = (const float*)d_in[1];
    const int*   eu       = (const int*)d_in[2];
    const int*   ei       = (const int*)d_in[3];
    const float* ew       = (const float*)d_in[4];
    const float* u_w      = (const float*)d_in[5];
    const float* i_w      = (const float*)d_in[6];
    const float* alpha    = (const float*)d_in[7];

    float* out      = (float*)d_out;
    float* multi_u  = out;                                      // [U][D]
    float* multi_i  = out + (size_t)U_N * D_N;                  // [I][D]
    float* single_u = out + (size_t)(U_N + I_N) * D_N;          // [B][U][D]
    float* single_i = single_u + (size_t)B_N * U_N * D_N;       // [B][I][D]

    // tB lives in multi_u's slot (consumed by gather_i, written by gather_u).
    float* tB = multi_u;                                        // 51.2 MB
    // ranks live in multi_i's slot (consumed by fill; gather_i writes after).
    int* rank_u = (int*)multi_i;                                // 8 MB
    int* rank_i = rank_u + NEDGE;                               // 8 MB (16 <= 25.6 MB)

    // d_ws: offs | bsum | pairs | tA  (~60.1 MB)
    int*  offs  = (int*)d_ws;                                   // NKEYS+1
    int*  bsum  = offs + (NKEYS + 1);                           // 512
    int2* pairs = (int2*)((char*)d_ws + ((((NKEYS + 1 + 512) * 4) + 255) & ~255));
    float* tA   = (float*)(pairs + NMEMB);                      // [I][D] 25.6 MB

    hipMemsetAsync(offs, 0, (size_t)(NKEYS + 1) * sizeof(int), stream);

    transform2_kernel<<<TBI + TBU, 256, 0, stream>>>(item_emb, user_emb,
                                                     u_w, i_w, tA, tB);
    count_kernel<<<(NMEMB + 255) / 256, 256, 0, stream>>>(eu, ei, offs,
                                                          rank_u, rank_i);
    scan1_kernel<<<SNBLK, 256, 0, stream>>>(offs, bsum);
    scan2_kernel<<<1, 512, 0, stream>>>(bsum, offs);
    scan3_kernel<<<SNBLK, 256, 0, stream>>>(offs, bsum);
    fill_kernel<<<(NMEMB + 255) / 256, 256, 0, stream>>>(eu, ei, ew, offs,
                                                         rank_u, rank_i, pairs);

    // i-side first: it reads tB (= multi_u slot, written by gather_u).
    gather_kernel<<<(I_N + 3) / 4, 256, 0, stream>>>(
        tB, pairs, offs, single_i, multi_i, I_N, NKEYU, alpha);
    gather_kernel<<<(U_N + 3) / 4, 256, 0, stream>>>(
        tA, pairs, offs, single_u, multi_u, U_N, 0, alpha);
}

// Round 5
// 740.792 us; speedup vs baseline: 9.7253x; 1.0028x over previous
//
#include <hip/hip_runtime.h>

#define U_N 100000
#define I_N 50000
#define D_N 128
#define B_N 4
#define E_N 500000
#define NEDGE (B_N * E_N)            // 2,000,000
#define NKEYU (4 * U_N)              // keys u*4+b
#define NKEYS (NKEYU + 4 * I_N)      // 600,000
#define NMEMB (2 * NEDGE)            // 4,000,000
#define SCHUNK 2048
#define SNBLK ((NKEYS + SCHUNK - 1) / SCHUNK)   // 293
#define TBI ((I_N + 31) / 32)        // transform blocks (item side)
#define TBU ((U_N + 31) / 32)        // transform blocks (user side)

// ---------------------------------------------------------------------------
// Fast zero of offs[NKEYS+1] (replaces pathologically slow rocclr fill).
// ---------------------------------------------------------------------------
__global__ __launch_bounds__(256) void zero_kernel(int4* __restrict__ p, int n4)
{
    int t = blockIdx.x * 256 + threadIdx.x;
    if (t < n4) p[t] = make_int4(0, 0, 0, 0);
}

// ---------------------------------------------------------------------------
// Fused transforms: tA = item_emb @ u_w, tB = user_emb @ i_w, one dispatch.
// ---------------------------------------------------------------------------
__global__ __launch_bounds__(256) void transform2_kernel(
    const float* __restrict__ item_emb, const float* __restrict__ user_emb,
    const float* __restrict__ u_w, const float* __restrict__ i_w,
    float* __restrict__ tA, float* __restrict__ tB)
{
    const float* X; const float* W; float* Y; int N; int blk;
    if (blockIdx.x < TBI) { X = item_emb; W = u_w; Y = tA; N = I_N; blk = blockIdx.x; }
    else                  { X = user_emb; W = i_w; Y = tB; N = U_N; blk = blockIdx.x - TBI; }

    __shared__ float wlds[D_N][D_N];
    for (int idx = threadIdx.x; idx < D_N * D_N / 4; idx += 256)
        reinterpret_cast<float4*>(&wlds[0][0])[idx] =
            reinterpret_cast<const float4*>(W)[idx];
    __syncthreads();

    int rr = threadIdx.x & 31;
    int cg = threadIdx.x >> 5;
    int c0 = cg * 16;
    int r  = blk * 32 + rr;
    bool valid = (r < N);
    int rc = valid ? r : (N - 1);
    const float* xrow = X + (size_t)rc * D_N;

    float4 acc[4];
    #pragma unroll
    for (int c = 0; c < 4; ++c) acc[c] = make_float4(0.f, 0.f, 0.f, 0.f);

    for (int k4 = 0; k4 < D_N / 4; ++k4) {
        float4 a = *reinterpret_cast<const float4*>(xrow + k4 * 4);
        #pragma unroll
        for (int kk = 0; kk < 4; ++kk) {
            float ak = (kk == 0) ? a.x : (kk == 1) ? a.y : (kk == 2) ? a.z : a.w;
            #pragma unroll
            for (int c = 0; c < 4; ++c) {
                const float4 wv = *reinterpret_cast<const float4*>(
                    &wlds[k4 * 4 + kk][c0 + c * 4]);
                acc[c].x += ak * wv.x;
                acc[c].y += ak * wv.y;
                acc[c].z += ak * wv.z;
                acc[c].w += ak * wv.w;
            }
        }
    }
    if (valid) {
        #pragma unroll
        for (int c = 0; c < 4; ++c)
            *reinterpret_cast<float4*>(Y + (size_t)r * D_N + c0 + c * 4) = acc[c];
    }
}

// ---------------------------------------------------------------------------
// Count + rank: one membership per thread; atomic return value = rank.
// ---------------------------------------------------------------------------
__global__ __launch_bounds__(256) void count_kernel(
    const int* __restrict__ eu, const int* __restrict__ ei,
    int* __restrict__ offs, int* __restrict__ rank_u, int* __restrict__ rank_i)
{
    int t = blockIdx.x * 256 + threadIdx.x;
    if (t >= NMEMB) return;
    if (t < NEDGE) {
        int e = t;
        int key = eu[e] * 4 + e / E_N;
        rank_u[e] = atomicAdd(&offs[key], 1);
    } else {
        int e = t - NEDGE;
        int key = NKEYU + ei[e] * 4 + e / E_N;
        rank_i[e] = atomicAdd(&offs[key], 1);
    }
}

// ---------------------------------------------------------------------------
// In-place hierarchical exclusive scan over offs[NKEYS].
// ---------------------------------------------------------------------------
__global__ __launch_bounds__(256) void scan1_kernel(
    int* __restrict__ offs, int* __restrict__ bsum)
{
    __shared__ int s[256];
    int base = blockIdx.x * SCHUNK + threadIdx.x * 8;
    int v[8]; int tsum = 0;
    #pragma unroll
    for (int j = 0; j < 8; ++j) {
        int idx = base + j;
        v[j] = (idx < NKEYS) ? offs[idx] : 0;
        tsum += v[j];
    }
    s[threadIdx.x] = tsum; __syncthreads();
    for (int off = 1; off < 256; off <<= 1) {
        int t = (threadIdx.x >= off) ? s[threadIdx.x - off] : 0;
        __syncthreads(); s[threadIdx.x] += t; __syncthreads();
    }
    int excl = s[threadIdx.x] - tsum;
    if (threadIdx.x == 255) bsum[blockIdx.x] = s[255];
    int run = excl;
    #pragma unroll
    for (int j = 0; j < 8; ++j) {
        int idx = base + j;
        if (idx < NKEYS) offs[idx] = run;
        run += v[j];
    }
}

__global__ __launch_bounds__(512) void scan2_kernel(int* __restrict__ bsum,
                                                    int* __restrict__ offs)
{
    __shared__ int s[512];
    int v = (threadIdx.x < SNBLK) ? bsum[threadIdx.x] : 0;
    s[threadIdx.x] = v; __syncthreads();
    for (int off = 1; off < 512; off <<= 1) {
        int t = (threadIdx.x >= off) ? s[threadIdx.x - off] : 0;
        __syncthreads(); s[threadIdx.x] += t; __syncthreads();
    }
    if (threadIdx.x < SNBLK) bsum[threadIdx.x] = s[threadIdx.x] - v;
    if (threadIdx.x == 511) offs[NKEYS] = s[511];
}

__global__ __launch_bounds__(256) void scan3_kernel(int* __restrict__ offs,
                                                    const int* __restrict__ bsum)
{
    int add = bsum[blockIdx.x];
    int base = blockIdx.x * SCHUNK + threadIdx.x * 8;
    #pragma unroll
    for (int j = 0; j < 8; ++j) {
        int idx = base + j;
        if (idx < NKEYS) offs[idx] += add;
    }
}

// ---------------------------------------------------------------------------
// Atomic-free fill: pos = offs[key] + precomputed rank.
// ---------------------------------------------------------------------------
__global__ __launch_bounds__(256) void fill_kernel(
    const int* __restrict__ eu, const int* __restrict__ ei,
    const float* __restrict__ ew,
    const int* __restrict__ offs,
    const int* __restrict__ rank_u, const int* __restrict__ rank_i,
    int2* __restrict__ pairs)
{
    int t = blockIdx.x * 256 + threadIdx.x;
    if (t >= NMEMB) return;
    if (t < NEDGE) {
        int e = t;
        int b = e / E_N;
        int key = eu[e] * 4 + b;
        int pos = offs[key] + rank_u[e];
        pairs[pos] = make_int2(ei[e], __float_as_int(ew[e]));
    } else {
        int e = t - NEDGE;
        int b = e / E_N;
        int key = NKEYU + ei[e] * 4 + b;
        int pos = offs[key] + rank_i[e];
        pairs[pos] = make_int2(eu[e], __float_as_int(ew[e]));
    }
}

// ---------------------------------------------------------------------------
// Gather: one wave per destination row; lanes own 2 floats; 2x-unrolled.
// ---------------------------------------------------------------------------
__global__ __launch_bounds__(256) void gather_kernel(
    const float* __restrict__ T,
    const int2* __restrict__ pairs,
    const int* __restrict__ offs,
    float* __restrict__ single,       // [B][N][D]
    float* __restrict__ multi,        // [N][D]
    int N, int keybase, const float* __restrict__ alpha_p)
{
    int r = blockIdx.x * 4 + (threadIdx.x >> 6);
    if (r >= N) return;
    float alpha = alpha_p[0];
    int lane = threadIdx.x & 63;
    int d = lane * 2;
    int k0 = keybase + r * 4;
    int beg = offs[k0];
    float mx = 0.f, my = 0.f;
    #pragma unroll
    for (int b = 0; b < 4; ++b) {
        int end = offs[k0 + b + 1];
        float ax = 0.f, ay = 0.f;
        int p = beg;
        for (; p + 1 < end; p += 2) {
            int2 pr0 = pairs[p];
            int2 pr1 = pairs[p + 1];
            float2 v0 = *reinterpret_cast<const float2*>(T + (size_t)pr0.x * D_N + d);
            float2 v1 = *reinterpret_cast<const float2*>(T + (size_t)pr1.x * D_N + d);
            float w0 = __int_as_float(pr0.y);
            float w1 = __int_as_float(pr1.y);
            ax += w0 * v0.x + w1 * v1.x;
            ay += w0 * v0.y + w1 * v1.y;
        }
        if (p < end) {
            int2 pr = pairs[p];
            float w = __int_as_float(pr.y);
            float2 v = *reinterpret_cast<const float2*>(T + (size_t)pr.x * D_N + d);
            ax += w * v.x;
            ay += w * v.y;
        }
        mx += ax; my += ay;
        float2 o;
        o.x = ax >= 0.f ? ax : alpha * ax;
        o.y = ay >= 0.f ? ay : alpha * ay;
        *reinterpret_cast<float2*>(single + ((size_t)b * N + r) * D_N + d) = o;
        beg = end;
    }
    mx *= 0.25f; my *= 0.25f;
    float2 o;
    o.x = mx >= 0.f ? mx : alpha * mx;
    o.y = my >= 0.f ? my : alpha * my;
    *reinterpret_cast<float2*>(multi + (size_t)r * D_N + d) = o;
}

extern "C" void kernel_launch(void* const* d_in, const int* in_sizes, int n_in,
                              void* d_out, int out_size, void* d_ws, size_t ws_size,
                              hipStream_t stream) {
    const float* user_emb = (const float*)d_in[0];
    const float* item_emb = (const float*)d_in[1];
    const int*   eu       = (const int*)d_in[2];
    const int*   ei       = (const int*)d_in[3];
    const float* ew       = (const float*)d_in[4];
    const float* u_w      = (const float*)d_in[5];
    const float* i_w      = (const float*)d_in[6];
    const float* alpha    = (const float*)d_in[7];

    float* out      = (float*)d_out;
    float* multi_u  = out;                                      // [U][D]
    float* multi_i  = out + (size_t)U_N * D_N;                  // [I][D]
    float* single_u = out + (size_t)(U_N + I_N) * D_N;          // [B][U][D]
    float* single_i = single_u + (size_t)B_N * U_N * D_N;       // [B][I][D]

    // tB lives in multi_u's slot (consumed by gather_i, written by gather_u).
    float* tB = multi_u;                                        // 51.2 MB
    // ranks live in multi_i's slot (consumed by fill; gather_i writes after).
    int* rank_u = (int*)multi_i;                                // 8 MB
    int* rank_i = rank_u + NEDGE;                               // 8 MB

    // d_ws: offs | bsum | pairs | tA  (~60.1 MB)
    int*  offs  = (int*)d_ws;                                   // NKEYS+1 (+pad)
    int*  bsum  = offs + (NKEYS + 4);                           // 512
    int2* pairs = (int2*)((char*)d_ws + ((((NKEYS + 4 + 512) * 4) + 255) & ~255));
    float* tA   = (float*)(pairs + NMEMB);                      // [I][D] 25.6 MB

    // fast zero of offs[0..NKEYS] (NKEYS+4 ints, 16B-aligned, n4 vectors)
    int n4 = (NKEYS + 4) / 4;
    zero_kernel<<<(n4 + 255) / 256, 256, 0, stream>>>((int4*)offs, n4);

    transform2_kernel<<<TBI + TBU, 256, 0, stream>>>(item_emb, user_emb,
                                                     u_w, i_w, tA, tB);
    count_kernel<<<(NMEMB + 255) / 256, 256, 0, stream>>>(eu, ei, offs,
                                                          rank_u, rank_i);
    scan1_kernel<<<SNBLK, 256, 0, stream>>>(offs, bsum);
    scan2_kernel<<<1, 512, 0, stream>>>(bsum, offs);
    scan3_kernel<<<SNBLK, 256, 0, stream>>>(offs, bsum);
    fill_kernel<<<(NMEMB + 255) / 256, 256, 0, stream>>>(eu, ei, ew, offs,
                                                         rank_u, rank_i, pairs);

    // i-side first: it reads tB (= multi_u slot, written by gather_u).
    gather_kernel<<<(I_N + 3) / 4, 256, 0, stream>>>(
        tB, pairs, offs, single_i, multi_i, I_N, NKEYU, alpha);
    gather_kernel<<<(U_N + 3) / 4, 256, 0, stream>>>(
        tA, pairs, offs, single_u, multi_u, U_N, 0, alpha);
}